// Round 9
// baseline (227.037 us; speedup 1.0000x reference)
//
#include <hip/hip_runtime.h>
#include <float.h>
#include <math.h>

#define NBATCH   4096
#define NAGENT   16
#define NTASK    16
#define DDIM     128
#define G        4      // batches per block (one per wave)
#define NTHREADS 256    // 4 waves -> 4 independent barrier groups per CU
#define SSEG     20     // scr segment stride (16 data + 4 pad dwords)

typedef float f32x2 __attribute__((ext_vector_type(2)));

// DPP quad_perm lane-xor (VALU pipe): xor1 = 0xB1, xor2 = 0x4E
template<int CTRL>
__device__ __forceinline__ float dppf(float x) {
    return __int_as_float(__builtin_amdgcn_update_dpp(
        0, __float_as_int(x), CTRL, 0xF, 0xF, true));
}
template<int CTRL>
__device__ __forceinline__ int dppi(int x) {
    return __builtin_amdgcn_update_dpp(0, x, CTRL, 0xF, 0xF, true);
}

// packed fp32 fma: acc.{lo,hi} += bcast(a.{lo|hi per SEL}) * b.{lo,hi}
// per-component IEEE fma -> bit-identical to two scalar v_fma_f32.
template<int SEL>
__device__ __forceinline__ void pk_fma_b(f32x2& acc, f32x2 a, f32x2 b) {
    if constexpr (SEL == 0)
        asm("v_pk_fma_f32 %0, %1, %2, %0 op_sel:[0,0,0] op_sel_hi:[0,1,1]"
            : "+v"(acc) : "v"(a), "v"(b));
    else
        asm("v_pk_fma_f32 %0, %1, %2, %0 op_sel:[1,0,0] op_sel_hi:[1,1,1]"
            : "+v"(acc) : "v"(a), "v"(b));
}

// Build lane-order permuted W copy in d_ws so the main kernel's per-step W
// stream is fully coalesced: wp[(c*8 + r*2 + half)*256 + t] =
// W_upd[(t&15)*16 + c*4 + r][(t>>4)*8 + half*4 .. +3]
__global__ void wperm_kernel(const float* __restrict__ W_upd,
                             float4* __restrict__ wp) {
    const int q    = blockIdx.x * 256 + threadIdx.x;   // 0..8191
    const int t    = q & 255;
    const int rh   = q >> 8;          // 0..31
    const int half = rh & 1;
    const int row4 = rh >> 1;         // c*4 + r
    const int i    = (t & 15) * 16 + row4;
    const int col  = (t >> 4) * 8 + half * 4;
    wp[q] = *(const float4*)(W_upd + (size_t)i * DDIM + col);
}

// 2nd launch_bounds arg behaves as BLOCKS/CU on hipcc (r2 evidence):
// (256,4) -> 16 waves/CU target -> 128-VGPR cap.
template<bool PERM>
__global__ __launch_bounds__(NTHREADS, 4)
void alloc_policy_kernel(const float* __restrict__ task_embeds,
                         const float* __restrict__ task_nonag,
                         const float* __restrict__ agent_embeds,
                         const unsigned char* __restrict__ task_mask,
                         const float* __restrict__ agent_mask,
                         const float* __restrict__ gumbels,
                         const float* __restrict__ W_count,
                         const float* __restrict__ b_count,
                         const float* __restrict__ W_upd,
                         const float* __restrict__ b_upd,
                         const float4* __restrict__ wperm,
                         float* __restrict__ out)
{
    // LDS 38.9 KB -> 4 blocks/CU fit
    __shared__ __align__(16) float te[G][NTASK][DDIM];     // 32 KB
    __shared__ __align__(16) float scr[G][16 * SSEG];      // 5 KB
    __shared__ __align__(16) float4 sdots4[G][NAGENT];     // 1 KB
    __shared__ __align__(16) float4 upd4[G];

    const int tid  = threadIdx.x;
    const int lane = tid & 63;
    const int w    = tid >> 6;            // wave id == batch slot g (0..3)
    const int b0   = blockIdx.x * G;
    const int gb_w = b0 + w;

    const bool h0 = (lane & 1) != 0;
    const bool h1 = (lane & 2) != 0;
    const bool h2 = (lane & 4) != 0;
    const bool h3 = (lane & 8) != 0;

    // phase-M mapping: colgroup cg owns 8 cols; iseg owns i in [iseg*16, +16)
    const int cg   = tid >> 4;            // 0..15
    const int iseg = tid & 15;
    // reduce leaves lane with j_lin = 16*hgi + (lane&15); col = cg*8 + (lane&7)
    // (same col for both hgi; g = 2*hgi + ((lane>>3)&1))  [r8 bug was here]
    const float bu = b_upd[cg * 8 + (lane & 7)];

    const float scalef = sqrtf(128.0f);

    // ---- init te (block-wide coalesced copy)
    {
        const float4* src = (const float4*)(task_embeds + (size_t)b0 * NTASK * DDIM);
        float4* dst = (float4*)(&te[0][0][0]);
        #pragma unroll
        for (int k = 0; k < (G * NTASK * DDIM / 4) / NTHREADS; ++k)  // 8
            dst[k * NTHREADS + tid] = src[k * NTHREADS + tid];
    }

    // ---- init sdots4 per (g,a): s0=dot(ag,Wc0), s1=dot(ag,Wc1), s2=dot(ag,bc)
    {
        const int p = tid >> 2, q = tid & 3;   // 64 (g,a) pairs x 4 quarters
        const int g = p >> 4,  a = p & 15;
        const float* agp = agent_embeds + ((size_t)(b0 + g) * NAGENT + a) * DDIM + q * 32;
        float a0 = 0.f, a1 = 0.f, a2 = 0.f;
        #pragma unroll
        for (int c = 0; c < 8; ++c) {
            const float4 av = *(const float4*)(agp + c * 4);
            const float4 w0 = *(const float4*)(W_count + q * 32 + c * 4);
            const float4 w1 = *(const float4*)(W_count + DDIM + q * 32 + c * 4);
            const float4 bc = *(const float4*)(b_count + q * 32 + c * 4);
            a0 = fmaf(av.x, w0.x, a0); a0 = fmaf(av.y, w0.y, a0);
            a0 = fmaf(av.z, w0.z, a0); a0 = fmaf(av.w, w0.w, a0);
            a1 = fmaf(av.x, w1.x, a1); a1 = fmaf(av.y, w1.y, a1);
            a1 = fmaf(av.z, w1.z, a1); a1 = fmaf(av.w, w1.w, a1);
            a2 = fmaf(av.x, bc.x, a2); a2 = fmaf(av.y, bc.y, a2);
            a2 = fmaf(av.z, bc.z, a2); a2 = fmaf(av.w, bc.w, a2);
        }
        a0 += __shfl_xor(a0, 1); a0 += __shfl_xor(a0, 2);
        a1 += __shfl_xor(a1, 1); a1 += __shfl_xor(a1, 2);
        a2 += __shfl_xor(a2, 1); a2 += __shfl_xor(a2, 2);
        if (q == 0) sdots4[g][a] = make_float4(a0, a1, a2, 0.f);
    }

    const int tau = lane & 15;
    const float nn_my = task_nonag[gb_w * NTASK + tau];
    const unsigned char mask_my = task_mask[gb_w * NTASK + tau];
    float cc_my = 0.0f;

    const float* agbase = agent_embeds + (size_t)gb_w * NAGENT * DDIM;
    float2 ag2 = *(const float2*)(agbase + lane * 2);                // a=0
    float  gum = gumbels[(size_t)gb_w * NTASK + tau];                // a=0
    float  amk = agent_mask[(size_t)gb_w * NAGENT + 0];

    __syncthreads();   // te + sdots4 ready

    for (int a = 0; a < NAGENT; ++a) {
        // ================= phase L: dots + packed butterfly (r5-verbatim) ====
        float v[16];
        #pragma unroll
        for (int t = 0; t < 16; ++t) {
            const float2 t2 = *(const float2*)(&te[w][t][lane * 2]);
            v[t] = fmaf(ag2.y, t2.y, ag2.x * t2.x);
        }
        float p8[8];
        #pragma unroll
        for (int m2 = 0; m2 < 8; ++m2) {
            const float lo = v[2 * m2], hi = v[2 * m2 + 1];
            const float send = h0 ? lo : hi;
            const float mine = h0 ? hi : lo;
            p8[m2] = mine + dppf<0xB1>(send);
        }
        float p4[4];
        #pragma unroll
        for (int m2 = 0; m2 < 4; ++m2) {
            const float lo = p8[2 * m2], hi = p8[2 * m2 + 1];
            const float send = h1 ? lo : hi;
            const float mine = h1 ? hi : lo;
            p4[m2] = mine + dppf<0x4E>(send);
        }
        float p2v[2];
        #pragma unroll
        for (int m2 = 0; m2 < 2; ++m2) {
            const float lo = p4[2 * m2], hi = p4[2 * m2 + 1];
            const float send = h2 ? lo : hi;
            const float mine = h2 ? hi : lo;
            p2v[m2] = mine + __shfl_xor(send, 4);
        }
        float p1;
        {
            const float lo = p2v[0], hi = p2v[1];
            const float send = h3 ? lo : hi;
            const float mine = h3 ? hi : lo;
            p1 = mine + __shfl_xor(send, 8);
        }
        p1 += __shfl_xor(p1, 16);
        p1 += __shfl_xor(p1, 32);

        // ================= phase S: softmax/argmax/output (r5-verbatim) ======
        const float4 sd = sdots4[w][a];
        const float dot_total = p1 + fmaf(nn_my, sd.x, fmaf(cc_my, sd.y, sd.z));
        float z = dot_total / scalef;
        if (mask_my) z = -FLT_MAX;
        z = z + gum;

        float mz = z;
        mz = fmaxf(mz, dppf<0xB1>(mz));
        mz = fmaxf(mz, dppf<0x4E>(mz));
        mz = fmaxf(mz, __shfl_xor(mz, 4));
        mz = fmaxf(mz, __shfl_xor(mz, 8));
        const float e = expf(z - mz);
        float ss = e;
        ss += dppf<0xB1>(ss);
        ss += dppf<0x4E>(ss);
        ss += __shfl_xor(ss, 4);
        ss += __shfl_xor(ss, 8);
        const float sft = e / ss;

        float mx = sft;
        mx = fmaxf(mx, dppf<0xB1>(mx));
        mx = fmaxf(mx, dppf<0x4E>(mx));
        mx = fmaxf(mx, __shfl_xor(mx, 4));
        mx = fmaxf(mx, __shfl_xor(mx, 8));
        int cand = (sft == mx) ? tau : NTASK;
        cand = min(cand, dppi<0xB1>(cand));
        cand = min(cand, dppi<0x4E>(cand));
        cand = min(cand, __shfl_xor(cand, 4));
        cand = min(cand, __shfl_xor(cand, 8));
        const int bi = cand;

        const float agm = 1.0f - amk;
        const float onehot = (tau == bi) ? 1.0f : 0.0f;
        const float hh = ((onehot - sft) + sft) * agm;   // exact 0 / exact agm

        if (lane < 16)
            out[((size_t)gb_w * NAGENT + a) * NTASK + tau] = hh;
        cc_my = cc_my + hh * 0.1f;
        if (lane < 16 && tau == bi)
            upd4[w] = make_float4(__int_as_float(bi), hh, agm, 0.f);

        // stage relu(concat(te[bi], ag)) into seg-strided scratch (r5-verbatim)
        {
            const float2 tsel = *(const float2*)(&te[w][bi][lane * 2]);
            float2 r0, r1;
            r0.x = fmaxf(tsel.x, 0.f); r0.y = fmaxf(tsel.y, 0.f);
            r1.x = fmaxf(ag2.x, 0.f);  r1.y = fmaxf(ag2.y, 0.f);
            const int i0 = 2 * lane;
            const int i1 = 128 + 2 * lane;
            *(float2*)(&scr[w][(i0 >> 4) * SSEG + (i0 & 15)]) = r0;
            *(float2*)(&scr[w][(i1 >> 4) * SSEG + (i1 & 15)]) = r1;
        }

        // prefetch next step's globals (hidden under phase M)
        const int an = (a + 1) & 15;
        const float2 ag2n = *(const float2*)(agbase + (size_t)an * DDIM + lane * 2);
        const float  gumn = gumbels[((size_t)an * NBATCH + gb_w) * NTASK + tau];
        const float  amkn = agent_mask[(size_t)gb_w * NAGENT + an];

        __syncthreads();   // barrier 1: scr + upd4 published

        // ============ phase M: packed matvec, W streamed coalesced ==========
        f32x2 acc2[16];    // acc2[g*4+p] = cols (2p, 2p+1) of group; A[8g+2p+e]
        #pragma unroll
        for (int j = 0; j < 16; ++j) acc2[j] = f32x2{0.f, 0.f};
        #pragma unroll
        for (int c = 0; c < 4; ++c) {
            float4 Wc[8];   // rh = r*2+half; rows r=0..3, cols half*4..+3
            if (PERM) {
                const float4* wp = wperm + tid;
                #pragma unroll
                for (int rh = 0; rh < 8; ++rh)
                    Wc[rh] = wp[(size_t)(c * 8 + rh) * 256];
            } else {
                #pragma unroll
                for (int r = 0; r < 4; ++r) {
                    const float* wrow = W_upd +
                        (size_t)(iseg * 16 + c * 4 + r) * DDIM + cg * 8;
                    Wc[r * 2]     = *(const float4*)(wrow);
                    Wc[r * 2 + 1] = *(const float4*)(wrow + 4);
                }
            }
            #pragma unroll
            for (int g = 0; g < G; ++g) {
                const float4 in4 = *(const float4*)(&scr[g][iseg * SSEG + c * 4]);
                const f32x2 ixy = f32x2{in4.x, in4.y};
                const f32x2 izw = f32x2{in4.z, in4.w};
                // row 0 (in.x)
                pk_fma_b<0>(acc2[g*4+0], ixy, f32x2{Wc[0].x, Wc[0].y});
                pk_fma_b<0>(acc2[g*4+1], ixy, f32x2{Wc[0].z, Wc[0].w});
                pk_fma_b<0>(acc2[g*4+2], ixy, f32x2{Wc[1].x, Wc[1].y});
                pk_fma_b<0>(acc2[g*4+3], ixy, f32x2{Wc[1].z, Wc[1].w});
                // row 1 (in.y)
                pk_fma_b<1>(acc2[g*4+0], ixy, f32x2{Wc[2].x, Wc[2].y});
                pk_fma_b<1>(acc2[g*4+1], ixy, f32x2{Wc[2].z, Wc[2].w});
                pk_fma_b<1>(acc2[g*4+2], ixy, f32x2{Wc[3].x, Wc[3].y});
                pk_fma_b<1>(acc2[g*4+3], ixy, f32x2{Wc[3].z, Wc[3].w});
                // row 2 (in.z)
                pk_fma_b<0>(acc2[g*4+0], izw, f32x2{Wc[4].x, Wc[4].y});
                pk_fma_b<0>(acc2[g*4+1], izw, f32x2{Wc[4].z, Wc[4].w});
                pk_fma_b<0>(acc2[g*4+2], izw, f32x2{Wc[5].x, Wc[5].y});
                pk_fma_b<0>(acc2[g*4+3], izw, f32x2{Wc[5].z, Wc[5].w});
                // row 3 (in.w)
                pk_fma_b<1>(acc2[g*4+0], izw, f32x2{Wc[6].x, Wc[6].y});
                pk_fma_b<1>(acc2[g*4+1], izw, f32x2{Wc[6].z, Wc[6].w});
                pk_fma_b<1>(acc2[g*4+2], izw, f32x2{Wc[7].x, Wc[7].y});
                pk_fma_b<1>(acc2[g*4+3], izw, f32x2{Wc[7].z, Wc[7].w});
            }
        }
        // packed reduce over iseg lanes (bits 0..3), r5-identical trees
        float q16[16];
        #pragma unroll
        for (int m2 = 0; m2 < 16; ++m2) {
            const float lo = acc2[m2].x, hi = acc2[m2].y;
            const float send = h0 ? lo : hi;
            const float mine = h0 ? hi : lo;
            q16[m2] = mine + dppf<0xB1>(send);
        }
        float q8[8];
        #pragma unroll
        for (int m2 = 0; m2 < 8; ++m2) {
            const float lo = q16[2 * m2], hi = q16[2 * m2 + 1];
            const float send = h1 ? lo : hi;
            const float mine = h1 ? hi : lo;
            q8[m2] = mine + dppf<0x4E>(send);
        }
        float q4[4];
        #pragma unroll
        for (int m2 = 0; m2 < 4; ++m2) {
            const float lo = q8[2 * m2], hi = q8[2 * m2 + 1];
            const float send = h2 ? lo : hi;
            const float mine = h2 ? hi : lo;
            q4[m2] = mine + __shfl_xor(send, 4);
        }
        float q2[2];
        #pragma unroll
        for (int m2 = 0; m2 < 2; ++m2) {
            const float lo = q4[2 * m2], hi = q4[2 * m2 + 1];
            const float send = h3 ? lo : hi;
            const float mine = h3 ? hi : lo;
            q2[m2] = mine + __shfl_xor(send, 8);
        }
        // epilogue (FIXED): lane holds j_lin = 16*hgi + (lane&15)
        //   -> g = 2*hgi + ((lane>>3)&1), col = cg*8 + (lane&7)
        #pragma unroll
        for (int hgi = 0; hgi < 2; ++hgi) {
            const int g = 2 * hgi + ((lane >> 3) & 1);
            const float4 u4 = upd4[g];
            const int ts = __float_as_int(u4.x);
            const float u = q2[hgi] + bu;
            const float addv = (u * u4.y) * u4.z;
            te[g][ts][cg * 8 + (lane & 7)] += addv;
        }
        __syncthreads();   // barrier 2: te fully updated

        ag2 = ag2n; gum = gumn; amk = amkn;
    }
}

extern "C" void kernel_launch(void* const* d_in, const int* in_sizes, int n_in,
                              void* d_out, int out_size, void* d_ws, size_t ws_size,
                              hipStream_t stream) {
    const float*         task_embeds  = (const float*)d_in[0];
    const float*         task_nonag   = (const float*)d_in[1];
    const float*         agent_embeds = (const float*)d_in[2];
    const unsigned char* task_mask    = (const unsigned char*)d_in[3];
    const float*         agent_mask   = (const float*)d_in[4];
    const float*         gumbels      = (const float*)d_in[5];
    const float*         W_count      = (const float*)d_in[6];
    const float*         b_count      = (const float*)d_in[7];
    const float*         W_upd        = (const float*)d_in[8];
    const float*         b_upd        = (const float*)d_in[9];
    float* out = (float*)d_out;

    dim3 grid(NBATCH / G);
    dim3 block(NTHREADS);

    if (ws_size >= 2 * DDIM * DDIM * sizeof(float)) {   // 128 KB for Wperm
        float4* wp = (float4*)d_ws;
        hipLaunchKernelGGL(wperm_kernel, dim3(32), dim3(256), 0, stream, W_upd, wp);
        hipLaunchKernelGGL(alloc_policy_kernel<true>, grid, block, 0, stream,
                           task_embeds, task_nonag, agent_embeds, task_mask,
                           agent_mask, gumbels, W_count, b_count, W_upd, b_upd,
                           wp, out);
    } else {
        hipLaunchKernelGGL(alloc_policy_kernel<false>, grid, block, 0, stream,
                           task_embeds, task_nonag, agent_embeds, task_mask,
                           agent_mask, gumbels, W_count, b_count, W_upd, b_upd,
                           (const float4*)nullptr, out);
    }
}

// Round 10
// 138.743 us; speedup vs baseline: 1.6364x; 1.6364x over previous
//
#include <hip/hip_runtime.h>
#include <float.h>
#include <math.h>

#define NBATCH   4096
#define NAGENT   16
#define NTASK    16
#define DDIM     128
#define G        4      // batches per block (one per wave)
#define NTHREADS 256    // 4 waves -> 4 independent barrier groups per CU
#define SSEG     20     // scr segment stride (16 data + 4 pad dwords)

typedef float f32x2 __attribute__((ext_vector_type(2)));

// DPP quad_perm lane-xor (VALU pipe): xor1 = 0xB1, xor2 = 0x4E
template<int CTRL>
__device__ __forceinline__ float dppf(float x) {
    return __int_as_float(__builtin_amdgcn_update_dpp(
        0, __float_as_int(x), CTRL, 0xF, 0xF, true));
}
template<int CTRL>
__device__ __forceinline__ int dppi(int x) {
    return __builtin_amdgcn_update_dpp(0, x, CTRL, 0xF, 0xF, true);
}

// packed fp32 fma: acc.{lo,hi} += bcast(a.{lo|hi per SEL}) * b.{lo,hi}
// per-component IEEE fma -> bit-identical to two scalar v_fma_f32.
template<int SEL>
__device__ __forceinline__ void pk_fma_b(f32x2& acc, f32x2 a, f32x2 b) {
    if constexpr (SEL == 0)
        asm("v_pk_fma_f32 %0, %1, %2, %0 op_sel:[0,0,0] op_sel_hi:[0,1,1]"
            : "+v"(acc) : "v"(a), "v"(b));
    else
        asm("v_pk_fma_f32 %0, %1, %2, %0 op_sel:[1,0,0] op_sel_hi:[1,1,1]"
            : "+v"(acc) : "v"(a), "v"(b));
}

// Build lane-order permuted W copy in d_ws so the main kernel's per-step W
// stream is fully coalesced: wp[(c*8 + r*2 + half)*256 + t] =
// W_upd[(t&15)*16 + c*4 + r][(t>>4)*8 + half*4 .. +3]
__global__ void wperm_kernel(const float* __restrict__ W_upd,
                             float4* __restrict__ wp) {
    const int q    = blockIdx.x * 256 + threadIdx.x;   // 0..8191
    const int t    = q & 255;
    const int rh   = q >> 8;          // 0..31
    const int half = rh & 1;
    const int row4 = rh >> 1;         // c*4 + r
    const int i    = (t & 15) * 16 + row4;
    const int col  = (t >> 4) * 8 + half * 4;
    wp[q] = *(const float4*)(W_upd + (size_t)i * DDIM + col);
}

// EMPIRICAL LAW (r2/r3/r9): hipcc VGPR cap = 256 / arg2.
// (256,4) -> 64-VGPR cap -> 460MB spill FETCH (r9). (256,2) -> 128 cap;
// 4 blocks/CU still fit: LDS 4x39.4KB <= 160KB, VGPR 16 waves x <=128 = pool.
template<bool PERM>
__global__ __launch_bounds__(NTHREADS, 2)
void alloc_policy_kernel(const float* __restrict__ task_embeds,
                         const float* __restrict__ task_nonag,
                         const float* __restrict__ agent_embeds,
                         const unsigned char* __restrict__ task_mask,
                         const float* __restrict__ agent_mask,
                         const float* __restrict__ gumbels,
                         const float* __restrict__ W_count,
                         const float* __restrict__ b_count,
                         const float* __restrict__ W_upd,
                         const float* __restrict__ b_upd,
                         const float4* __restrict__ wperm,
                         float* __restrict__ out)
{
    // LDS 38.9 KB -> 4 blocks/CU fit
    __shared__ __align__(16) float te[G][NTASK][DDIM];     // 32 KB
    __shared__ __align__(16) float scr[G][16 * SSEG];      // 5 KB
    __shared__ __align__(16) float4 sdots4[G][NAGENT];     // 1 KB
    __shared__ __align__(16) float4 upd4[G];

    const int tid  = threadIdx.x;
    const int lane = tid & 63;
    const int w    = tid >> 6;            // wave id == batch slot g (0..3)
    const int b0   = blockIdx.x * G;
    const int gb_w = b0 + w;

    const bool h0 = (lane & 1) != 0;
    const bool h1 = (lane & 2) != 0;
    const bool h2 = (lane & 4) != 0;
    const bool h3 = (lane & 8) != 0;

    // phase-M mapping: colgroup cg owns 8 cols; iseg owns i in [iseg*16, +16)
    const int cg   = tid >> 4;            // 0..15
    const int iseg = tid & 15;
    // reduce leaves lane with j_lin = 16*hgi + (lane&15); col = cg*8 + (lane&7)
    // (same col for both hgi; g = 2*hgi + ((lane>>3)&1))
    const float bu = b_upd[cg * 8 + (lane & 7)];

    const float scalef = sqrtf(128.0f);

    // ---- init te (block-wide coalesced copy)
    {
        const float4* src = (const float4*)(task_embeds + (size_t)b0 * NTASK * DDIM);
        float4* dst = (float4*)(&te[0][0][0]);
        #pragma unroll
        for (int k = 0; k < (G * NTASK * DDIM / 4) / NTHREADS; ++k)  // 8
            dst[k * NTHREADS + tid] = src[k * NTHREADS + tid];
    }

    // ---- init sdots4 per (g,a): s0=dot(ag,Wc0), s1=dot(ag,Wc1), s2=dot(ag,bc)
    {
        const int p = tid >> 2, q = tid & 3;   // 64 (g,a) pairs x 4 quarters
        const int g = p >> 4,  a = p & 15;
        const float* agp = agent_embeds + ((size_t)(b0 + g) * NAGENT + a) * DDIM + q * 32;
        float a0 = 0.f, a1 = 0.f, a2 = 0.f;
        #pragma unroll
        for (int c = 0; c < 8; ++c) {
            const float4 av = *(const float4*)(agp + c * 4);
            const float4 w0 = *(const float4*)(W_count + q * 32 + c * 4);
            const float4 w1 = *(const float4*)(W_count + DDIM + q * 32 + c * 4);
            const float4 bc = *(const float4*)(b_count + q * 32 + c * 4);
            a0 = fmaf(av.x, w0.x, a0); a0 = fmaf(av.y, w0.y, a0);
            a0 = fmaf(av.z, w0.z, a0); a0 = fmaf(av.w, w0.w, a0);
            a1 = fmaf(av.x, w1.x, a1); a1 = fmaf(av.y, w1.y, a1);
            a1 = fmaf(av.z, w1.z, a1); a1 = fmaf(av.w, w1.w, a1);
            a2 = fmaf(av.x, bc.x, a2); a2 = fmaf(av.y, bc.y, a2);
            a2 = fmaf(av.z, bc.z, a2); a2 = fmaf(av.w, bc.w, a2);
        }
        a0 += __shfl_xor(a0, 1); a0 += __shfl_xor(a0, 2);
        a1 += __shfl_xor(a1, 1); a1 += __shfl_xor(a1, 2);
        a2 += __shfl_xor(a2, 1); a2 += __shfl_xor(a2, 2);
        if (q == 0) sdots4[g][a] = make_float4(a0, a1, a2, 0.f);
    }

    const int tau = lane & 15;
    const float nn_my = task_nonag[gb_w * NTASK + tau];
    const unsigned char mask_my = task_mask[gb_w * NTASK + tau];
    float cc_my = 0.0f;

    const float* agbase = agent_embeds + (size_t)gb_w * NAGENT * DDIM;
    float2 ag2 = *(const float2*)(agbase + lane * 2);                // a=0
    float  gum = gumbels[(size_t)gb_w * NTASK + tau];                // a=0
    float  amk = agent_mask[(size_t)gb_w * NAGENT + 0];

    __syncthreads();   // te + sdots4 ready

    for (int a = 0; a < NAGENT; ++a) {
        // ================= phase L: dots + packed butterfly (r5-verbatim) ====
        float v[16];
        #pragma unroll
        for (int t = 0; t < 16; ++t) {
            const float2 t2 = *(const float2*)(&te[w][t][lane * 2]);
            v[t] = fmaf(ag2.y, t2.y, ag2.x * t2.x);
        }
        float p8[8];
        #pragma unroll
        for (int m2 = 0; m2 < 8; ++m2) {
            const float lo = v[2 * m2], hi = v[2 * m2 + 1];
            const float send = h0 ? lo : hi;
            const float mine = h0 ? hi : lo;
            p8[m2] = mine + dppf<0xB1>(send);
        }
        float p4[4];
        #pragma unroll
        for (int m2 = 0; m2 < 4; ++m2) {
            const float lo = p8[2 * m2], hi = p8[2 * m2 + 1];
            const float send = h1 ? lo : hi;
            const float mine = h1 ? hi : lo;
            p4[m2] = mine + dppf<0x4E>(send);
        }
        float p2v[2];
        #pragma unroll
        for (int m2 = 0; m2 < 2; ++m2) {
            const float lo = p4[2 * m2], hi = p4[2 * m2 + 1];
            const float send = h2 ? lo : hi;
            const float mine = h2 ? hi : lo;
            p2v[m2] = mine + __shfl_xor(send, 4);
        }
        float p1;
        {
            const float lo = p2v[0], hi = p2v[1];
            const float send = h3 ? lo : hi;
            const float mine = h3 ? hi : lo;
            p1 = mine + __shfl_xor(send, 8);
        }
        p1 += __shfl_xor(p1, 16);
        p1 += __shfl_xor(p1, 32);

        // ================= phase S: softmax/argmax/output (r5-verbatim) ======
        const float4 sd = sdots4[w][a];
        const float dot_total = p1 + fmaf(nn_my, sd.x, fmaf(cc_my, sd.y, sd.z));
        float z = dot_total / scalef;
        if (mask_my) z = -FLT_MAX;
        z = z + gum;

        float mz = z;
        mz = fmaxf(mz, dppf<0xB1>(mz));
        mz = fmaxf(mz, dppf<0x4E>(mz));
        mz = fmaxf(mz, __shfl_xor(mz, 4));
        mz = fmaxf(mz, __shfl_xor(mz, 8));
        const float e = expf(z - mz);
        float ss = e;
        ss += dppf<0xB1>(ss);
        ss += dppf<0x4E>(ss);
        ss += __shfl_xor(ss, 4);
        ss += __shfl_xor(ss, 8);
        const float sft = e / ss;

        float mx = sft;
        mx = fmaxf(mx, dppf<0xB1>(mx));
        mx = fmaxf(mx, dppf<0x4E>(mx));
        mx = fmaxf(mx, __shfl_xor(mx, 4));
        mx = fmaxf(mx, __shfl_xor(mx, 8));
        int cand = (sft == mx) ? tau : NTASK;
        cand = min(cand, dppi<0xB1>(cand));
        cand = min(cand, dppi<0x4E>(cand));
        cand = min(cand, __shfl_xor(cand, 4));
        cand = min(cand, __shfl_xor(cand, 8));
        const int bi = cand;

        const float agm = 1.0f - amk;
        const float onehot = (tau == bi) ? 1.0f : 0.0f;
        const float hh = ((onehot - sft) + sft) * agm;   // exact 0 / exact agm

        if (lane < 16)
            out[((size_t)gb_w * NAGENT + a) * NTASK + tau] = hh;
        cc_my = cc_my + hh * 0.1f;
        if (lane < 16 && tau == bi)
            upd4[w] = make_float4(__int_as_float(bi), hh, agm, 0.f);

        // stage relu(concat(te[bi], ag)) into seg-strided scratch (r5-verbatim)
        {
            const float2 tsel = *(const float2*)(&te[w][bi][lane * 2]);
            float2 r0, r1;
            r0.x = fmaxf(tsel.x, 0.f); r0.y = fmaxf(tsel.y, 0.f);
            r1.x = fmaxf(ag2.x, 0.f);  r1.y = fmaxf(ag2.y, 0.f);
            const int i0 = 2 * lane;
            const int i1 = 128 + 2 * lane;
            *(float2*)(&scr[w][(i0 >> 4) * SSEG + (i0 & 15)]) = r0;
            *(float2*)(&scr[w][(i1 >> 4) * SSEG + (i1 & 15)]) = r1;
        }

        // prefetch next step's globals (hidden under phase M)
        const int an = (a + 1) & 15;
        const float2 ag2n = *(const float2*)(agbase + (size_t)an * DDIM + lane * 2);
        const float  gumn = gumbels[((size_t)an * NBATCH + gb_w) * NTASK + tau];
        const float  amkn = agent_mask[(size_t)gb_w * NAGENT + an];

        __syncthreads();   // barrier 1: scr + upd4 published

        // ============ phase M: packed matvec, W streamed coalesced ==========
        f32x2 acc2[16];    // acc2[g*4+p] = cols (2p, 2p+1) of group; A[8g+2p+e]
        #pragma unroll
        for (int j = 0; j < 16; ++j) acc2[j] = f32x2{0.f, 0.f};
        #pragma unroll
        for (int c = 0; c < 4; ++c) {
            float4 Wc[8];   // rh = r*2+half; rows r=0..3, cols half*4..+3
            if (PERM) {
                const float4* wp = wperm + tid;
                #pragma unroll
                for (int rh = 0; rh < 8; ++rh)
                    Wc[rh] = wp[(size_t)(c * 8 + rh) * 256];
            } else {
                #pragma unroll
                for (int r = 0; r < 4; ++r) {
                    const float* wrow = W_upd +
                        (size_t)(iseg * 16 + c * 4 + r) * DDIM + cg * 8;
                    Wc[r * 2]     = *(const float4*)(wrow);
                    Wc[r * 2 + 1] = *(const float4*)(wrow + 4);
                }
            }
            #pragma unroll
            for (int g = 0; g < G; ++g) {
                const float4 in4 = *(const float4*)(&scr[g][iseg * SSEG + c * 4]);
                const f32x2 ixy = f32x2{in4.x, in4.y};
                const f32x2 izw = f32x2{in4.z, in4.w};
                // row 0 (in.x)
                pk_fma_b<0>(acc2[g*4+0], ixy, f32x2{Wc[0].x, Wc[0].y});
                pk_fma_b<0>(acc2[g*4+1], ixy, f32x2{Wc[0].z, Wc[0].w});
                pk_fma_b<0>(acc2[g*4+2], ixy, f32x2{Wc[1].x, Wc[1].y});
                pk_fma_b<0>(acc2[g*4+3], ixy, f32x2{Wc[1].z, Wc[1].w});
                // row 1 (in.y)
                pk_fma_b<1>(acc2[g*4+0], ixy, f32x2{Wc[2].x, Wc[2].y});
                pk_fma_b<1>(acc2[g*4+1], ixy, f32x2{Wc[2].z, Wc[2].w});
                pk_fma_b<1>(acc2[g*4+2], ixy, f32x2{Wc[3].x, Wc[3].y});
                pk_fma_b<1>(acc2[g*4+3], ixy, f32x2{Wc[3].z, Wc[3].w});
                // row 2 (in.z)
                pk_fma_b<0>(acc2[g*4+0], izw, f32x2{Wc[4].x, Wc[4].y});
                pk_fma_b<0>(acc2[g*4+1], izw, f32x2{Wc[4].z, Wc[4].w});
                pk_fma_b<0>(acc2[g*4+2], izw, f32x2{Wc[5].x, Wc[5].y});
                pk_fma_b<0>(acc2[g*4+3], izw, f32x2{Wc[5].z, Wc[5].w});
                // row 3 (in.w)
                pk_fma_b<1>(acc2[g*4+0], izw, f32x2{Wc[6].x, Wc[6].y});
                pk_fma_b<1>(acc2[g*4+1], izw, f32x2{Wc[6].z, Wc[6].w});
                pk_fma_b<1>(acc2[g*4+2], izw, f32x2{Wc[7].x, Wc[7].y});
                pk_fma_b<1>(acc2[g*4+3], izw, f32x2{Wc[7].z, Wc[7].w});
            }
        }
        // packed reduce over iseg lanes (bits 0..3), r5-identical trees
        float q16[16];
        #pragma unroll
        for (int m2 = 0; m2 < 16; ++m2) {
            const float lo = acc2[m2].x, hi = acc2[m2].y;
            const float send = h0 ? lo : hi;
            const float mine = h0 ? hi : lo;
            q16[m2] = mine + dppf<0xB1>(send);
        }
        float q8[8];
        #pragma unroll
        for (int m2 = 0; m2 < 8; ++m2) {
            const float lo = q16[2 * m2], hi = q16[2 * m2 + 1];
            const float send = h1 ? lo : hi;
            const float mine = h1 ? hi : lo;
            q8[m2] = mine + dppf<0x4E>(send);
        }
        float q4[4];
        #pragma unroll
        for (int m2 = 0; m2 < 4; ++m2) {
            const float lo = q8[2 * m2], hi = q8[2 * m2 + 1];
            const float send = h2 ? lo : hi;
            const float mine = h2 ? hi : lo;
            q4[m2] = mine + __shfl_xor(send, 4);
        }
        float q2[2];
        #pragma unroll
        for (int m2 = 0; m2 < 2; ++m2) {
            const float lo = q4[2 * m2], hi = q4[2 * m2 + 1];
            const float send = h3 ? lo : hi;
            const float mine = h3 ? hi : lo;
            q2[m2] = mine + __shfl_xor(send, 8);
        }
        // epilogue: lane holds j_lin = 16*hgi + (lane&15)
        //   -> g = 2*hgi + ((lane>>3)&1), col = cg*8 + (lane&7)
        #pragma unroll
        for (int hgi = 0; hgi < 2; ++hgi) {
            const int g = 2 * hgi + ((lane >> 3) & 1);
            const float4 u4 = upd4[g];
            const int ts = __float_as_int(u4.x);
            const float u = q2[hgi] + bu;
            const float addv = (u * u4.y) * u4.z;
            te[g][ts][cg * 8 + (lane & 7)] += addv;
        }
        __syncthreads();   // barrier 2: te fully updated

        ag2 = ag2n; gum = gumn; amk = amkn;
    }
}

extern "C" void kernel_launch(void* const* d_in, const int* in_sizes, int n_in,
                              void* d_out, int out_size, void* d_ws, size_t ws_size,
                              hipStream_t stream) {
    const float*         task_embeds  = (const float*)d_in[0];
    const float*         task_nonag   = (const float*)d_in[1];
    const float*         agent_embeds = (const float*)d_in[2];
    const unsigned char* task_mask    = (const unsigned char*)d_in[3];
    const float*         agent_mask   = (const float*)d_in[4];
    const float*         gumbels      = (const float*)d_in[5];
    const float*         W_count      = (const float*)d_in[6];
    const float*         b_count      = (const float*)d_in[7];
    const float*         W_upd        = (const float*)d_in[8];
    const float*         b_upd        = (const float*)d_in[9];
    float* out = (float*)d_out;

    dim3 grid(NBATCH / G);
    dim3 block(NTHREADS);

    if (ws_size >= 2 * DDIM * DDIM * sizeof(float)) {   // 128 KB for Wperm
        float4* wp = (float4*)d_ws;
        hipLaunchKernelGGL(wperm_kernel, dim3(32), dim3(256), 0, stream, W_upd, wp);
        hipLaunchKernelGGL(alloc_policy_kernel<true>, grid, block, 0, stream,
                           task_embeds, task_nonag, agent_embeds, task_mask,
                           agent_mask, gumbels, W_count, b_count, W_upd, b_upd,
                           wp, out);
    } else {
        hipLaunchKernelGGL(alloc_policy_kernel<false>, grid, block, 0, stream,
                           task_embeds, task_nonag, agent_embeds, task_mask,
                           agent_mask, gumbels, W_count, b_count, W_upd, b_upd,
                           (const float4*)nullptr, out);
    }
}

// Round 11
// 111.678 us; speedup vs baseline: 2.0330x; 1.2423x over previous
//
#include <hip/hip_runtime.h>
#include <float.h>
#include <math.h>

#define NBATCH   4096
#define NAGENT   16
#define NTASK    16
#define DDIM     128
#define G        8      // batches per block (one per wave)
#define NTHREADS 512    // 8 waves
#define SSEG     20     // scr segment stride (16 data + 4 pad dwords)

typedef float f32x2 __attribute__((ext_vector_type(2)));

// DPP quad_perm lane-xor (VALU pipe): xor1 = 0xB1, xor2 = 0x4E
template<int CTRL>
__device__ __forceinline__ float dppf(float x) {
    return __int_as_float(__builtin_amdgcn_update_dpp(
        0, __float_as_int(x), CTRL, 0xF, 0xF, true));
}
template<int CTRL>
__device__ __forceinline__ int dppi(int x) {
    return __builtin_amdgcn_update_dpp(0, x, CTRL, 0xF, 0xF, true);
}

// packed fp32 fma: acc.{lo,hi} += bcast(a.{lo|hi per SEL}) * b.{lo,hi}
// per-component IEEE fma -> bit-identical to two scalar v_fma_f32.
template<int SEL>
__device__ __forceinline__ void pk_fma_b(f32x2& acc, f32x2 a, f32x2 b) {
    if constexpr (SEL == 0)
        asm("v_pk_fma_f32 %0, %1, %2, %0 op_sel:[0,0,0] op_sel_hi:[0,1,1]"
            : "+v"(acc) : "v"(a), "v"(b));
    else
        asm("v_pk_fma_f32 %0, %1, %2, %0 op_sel:[1,0,0] op_sel_hi:[1,1,1]"
            : "+v"(acc) : "v"(a), "v"(b));
}

// OCCUPANCY LAW (r2/r3/r5/r9/r10): __launch_bounds__ arg2 on hipcc clamps
// achieved residency to EXACTLY arg2 waves/EU (min=max in amdgpu-waves-per-eu)
// and caps VGPR at 256/arg2. To get VGPR budget 128 AND >2 waves/EU, use the
// raw attribute with separate min/max: min 4/EU (budget 128 >= our 88),
// max 8/EU (no clamp). LDS 78.3KB x 2 blocks = 156.6KB <= 160KB -> 2 blocks/CU.
__global__ __launch_bounds__(NTHREADS)
__attribute__((amdgpu_waves_per_eu(4, 8)))
void alloc_policy_kernel(const float* __restrict__ task_embeds,
                         const float* __restrict__ task_nonag,
                         const float* __restrict__ agent_embeds,
                         const unsigned char* __restrict__ task_mask,
                         const float* __restrict__ agent_mask,
                         const float* __restrict__ gumbels,
                         const float* __restrict__ W_count,
                         const float* __restrict__ b_count,
                         const float* __restrict__ W_upd,
                         const float* __restrict__ b_upd,
                         float* __restrict__ out)
{
    __shared__ __align__(16) float te[G][NTASK][DDIM];     // 64 KB
    __shared__ __align__(16) float scr[G][16 * SSEG];      // 10 KB
    __shared__ __align__(16) float4 sdots4[G][NAGENT];     // 2 KB
    __shared__ __align__(16) float4 upd4[G];

    const int tid  = threadIdx.x;
    const int lane = tid & 63;
    const int w    = tid >> 6;
    const int b0   = blockIdx.x * G;
    const int gb_w = b0 + w;

    const bool h0 = (lane & 1) != 0;
    const bool h1 = (lane & 2) != 0;
    const bool h2 = (lane & 4) != 0;
    const bool h3 = (lane & 8) != 0;

    // phase-M mapping: colgroup cg owns cols cg*4..cg*4+3; iseg owns i in [iseg*16, +16)
    const int cg   = tid >> 4;            // 0..31
    const int iseg = tid & 15;
    const float bu = b_upd[cg * 4 + (tid & 3)];

    const float scalef = sqrtf(128.0f);

    // ---- W slice -> 64 VGPRs as col-pairs (the r5 win: zero per-step W traffic)
    f32x2 W01[16], W23[16];   // [c*4+di]: (cols 0,1) and (cols 2,3) of row iseg*16+c*4+di
    #pragma unroll
    for (int c = 0; c < 4; ++c)
        #pragma unroll
        for (int di = 0; di < 4; ++di) {
            const float4 wv = *(const float4*)(W_upd +
                (size_t)(iseg * 16 + c * 4 + di) * DDIM + cg * 4);
            W01[c * 4 + di] = f32x2{wv.x, wv.y};
            W23[c * 4 + di] = f32x2{wv.z, wv.w};
        }

    // ---- init te
    {
        const float4* src = (const float4*)(task_embeds + (size_t)b0 * NTASK * DDIM);
        float4* dst = (float4*)(&te[0][0][0]);
        #pragma unroll
        for (int k = 0; k < (G * NTASK * DDIM / 4) / NTHREADS; ++k)  // 8
            dst[k * NTHREADS + tid] = src[k * NTHREADS + tid];
    }

    // ---- init sdots4 per (g,a): s0=dot(ag,Wc0), s1=dot(ag,Wc1), s2=dot(ag,bc)
    {
        const int p = tid >> 2, q = tid & 3;
        const int g = p >> 4,  a = p & 15;
        const float* agp = agent_embeds + ((size_t)(b0 + g) * NAGENT + a) * DDIM + q * 32;
        float a0 = 0.f, a1 = 0.f, a2 = 0.f;
        #pragma unroll
        for (int c = 0; c < 8; ++c) {
            const float4 av = *(const float4*)(agp + c * 4);
            const float4 w0 = *(const float4*)(W_count + q * 32 + c * 4);
            const float4 w1 = *(const float4*)(W_count + DDIM + q * 32 + c * 4);
            const float4 bc = *(const float4*)(b_count + q * 32 + c * 4);
            a0 = fmaf(av.x, w0.x, a0); a0 = fmaf(av.y, w0.y, a0);
            a0 = fmaf(av.z, w0.z, a0); a0 = fmaf(av.w, w0.w, a0);
            a1 = fmaf(av.x, w1.x, a1); a1 = fmaf(av.y, w1.y, a1);
            a1 = fmaf(av.z, w1.z, a1); a1 = fmaf(av.w, w1.w, a1);
            a2 = fmaf(av.x, bc.x, a2); a2 = fmaf(av.y, bc.y, a2);
            a2 = fmaf(av.z, bc.z, a2); a2 = fmaf(av.w, bc.w, a2);
        }
        a0 += __shfl_xor(a0, 1); a0 += __shfl_xor(a0, 2);
        a1 += __shfl_xor(a1, 1); a1 += __shfl_xor(a1, 2);
        a2 += __shfl_xor(a2, 1); a2 += __shfl_xor(a2, 2);
        if (q == 0) sdots4[g][a] = make_float4(a0, a1, a2, 0.f);
    }

    const int tau = lane & 15;
    const float nn_my = task_nonag[gb_w * NTASK + tau];
    const unsigned char mask_my = task_mask[gb_w * NTASK + tau];
    float cc_my = 0.0f;

    const float* agbase = agent_embeds + (size_t)gb_w * NAGENT * DDIM;
    float2 ag2 = *(const float2*)(agbase + lane * 2);                // a=0
    float  gum = gumbels[(size_t)gb_w * NTASK + tau];                // a=0
    float  amk = agent_mask[(size_t)gb_w * NAGENT + 0];

    __syncthreads();

    for (int a = 0; a < NAGENT; ++a) {
        // ================= phase L (wave-private) =================
        float v[16];
        #pragma unroll
        for (int t = 0; t < 16; ++t) {
            const float2 t2 = *(const float2*)(&te[w][t][lane * 2]);
            v[t] = fmaf(ag2.y, t2.y, ag2.x * t2.x);
        }
        float p8[8];
        #pragma unroll
        for (int m2 = 0; m2 < 8; ++m2) {
            const float lo = v[2 * m2], hi = v[2 * m2 + 1];
            const float send = h0 ? lo : hi;
            const float mine = h0 ? hi : lo;
            p8[m2] = mine + dppf<0xB1>(send);
        }
        float p4[4];
        #pragma unroll
        for (int m2 = 0; m2 < 4; ++m2) {
            const float lo = p8[2 * m2], hi = p8[2 * m2 + 1];
            const float send = h1 ? lo : hi;
            const float mine = h1 ? hi : lo;
            p4[m2] = mine + dppf<0x4E>(send);
        }
        float p2v[2];
        #pragma unroll
        for (int m2 = 0; m2 < 2; ++m2) {
            const float lo = p4[2 * m2], hi = p4[2 * m2 + 1];
            const float send = h2 ? lo : hi;
            const float mine = h2 ? hi : lo;
            p2v[m2] = mine + __shfl_xor(send, 4);
        }
        float p1;
        {
            const float lo = p2v[0], hi = p2v[1];
            const float send = h3 ? lo : hi;
            const float mine = h3 ? hi : lo;
            p1 = mine + __shfl_xor(send, 8);
        }
        p1 += __shfl_xor(p1, 16);
        p1 += __shfl_xor(p1, 32);   // all 64 lanes: full dot(ag, te[tau])

        // ================= phase S: softmax/argmax/output ====================
        const float4 sd = sdots4[w][a];
        const float dot_total = p1 + fmaf(nn_my, sd.x, fmaf(cc_my, sd.y, sd.z));
        float z = dot_total / scalef;
        if (mask_my) z = -FLT_MAX;
        z = z + gum;

        float mz = z;
        mz = fmaxf(mz, dppf<0xB1>(mz));
        mz = fmaxf(mz, dppf<0x4E>(mz));
        mz = fmaxf(mz, __shfl_xor(mz, 4));
        mz = fmaxf(mz, __shfl_xor(mz, 8));
        const float e = expf(z - mz);
        float ss = e;
        ss += dppf<0xB1>(ss);
        ss += dppf<0x4E>(ss);
        ss += __shfl_xor(ss, 4);
        ss += __shfl_xor(ss, 8);
        const float sft = e / ss;

        float mx = sft;
        mx = fmaxf(mx, dppf<0xB1>(mx));
        mx = fmaxf(mx, dppf<0x4E>(mx));
        mx = fmaxf(mx, __shfl_xor(mx, 4));
        mx = fmaxf(mx, __shfl_xor(mx, 8));
        int cand = (sft == mx) ? tau : NTASK;
        cand = min(cand, dppi<0xB1>(cand));
        cand = min(cand, dppi<0x4E>(cand));
        cand = min(cand, __shfl_xor(cand, 4));
        cand = min(cand, __shfl_xor(cand, 8));
        const int bi = cand;

        const float agm = 1.0f - amk;
        const float onehot = (tau == bi) ? 1.0f : 0.0f;
        const float hh = ((onehot - sft) + sft) * agm;   // exact 0 / exact agm

        if (lane < 16)
            out[((size_t)gb_w * NAGENT + a) * NTASK + tau] = hh;
        cc_my = cc_my + hh * 0.1f;
        if (lane < 16 && tau == bi)
            upd4[w] = make_float4(__int_as_float(bi), hh, agm, 0.f);

        // stage relu(concat(te[bi], ag)) into seg-strided scratch
        {
            const float2 tsel = *(const float2*)(&te[w][bi][lane * 2]);
            float2 r0, r1;
            r0.x = fmaxf(tsel.x, 0.f); r0.y = fmaxf(tsel.y, 0.f);
            r1.x = fmaxf(ag2.x, 0.f);  r1.y = fmaxf(ag2.y, 0.f);
            const int i0 = 2 * lane;
            const int i1 = 128 + 2 * lane;
            *(float2*)(&scr[w][(i0 >> 4) * SSEG + (i0 & 15)]) = r0;
            *(float2*)(&scr[w][(i1 >> 4) * SSEG + (i1 & 15)]) = r1;
        }

        // prefetch next step's globals (latency hidden under phase M)
        const int an = (a + 1) & 15;
        const float2 ag2n = *(const float2*)(agbase + (size_t)an * DDIM + lane * 2);
        const float  gumn = gumbels[((size_t)an * NBATCH + gb_w) * NTASK + tau];
        const float  amkn = agent_mask[(size_t)gb_w * NAGENT + an];

        __syncthreads();   // barrier 1: scr + upd4 published

        // ================= phase M: packed-fp32 matvec, all 8 g =============
        f32x2 acc01[G], acc23[G];
        #pragma unroll
        for (int g = 0; g < G; ++g) { acc01[g] = f32x2{0.f, 0.f}; acc23[g] = f32x2{0.f, 0.f}; }
        #pragma unroll
        for (int c = 0; c < 4; ++c) {
            const int sb = iseg * SSEG + c * 4;
            #pragma unroll
            for (int g = 0; g < 8; ++g) {
                const float4 in4 = *(const float4*)(&scr[g][sb]);
                const f32x2 ixy = f32x2{in4.x, in4.y};
                const f32x2 izw = f32x2{in4.z, in4.w};
                pk_fma_b<0>(acc01[g], ixy, W01[c * 4 + 0]);   // in.x * row di=0
                pk_fma_b<1>(acc01[g], ixy, W01[c * 4 + 1]);   // in.y * row di=1
                pk_fma_b<0>(acc01[g], izw, W01[c * 4 + 2]);   // in.z * row di=2
                pk_fma_b<1>(acc01[g], izw, W01[c * 4 + 3]);   // in.w * row di=3
                pk_fma_b<0>(acc23[g], ixy, W23[c * 4 + 0]);
                pk_fma_b<1>(acc23[g], ixy, W23[c * 4 + 1]);
                pk_fma_b<0>(acc23[g], izw, W23[c * 4 + 2]);
                pk_fma_b<1>(acc23[g], izw, W23[c * 4 + 3]);
            }
        }
        // packed reduce over iseg lanes (bits 0..3): 32 -> 2 values per lane
        float q16[16];
        #pragma unroll
        for (int m2 = 0; m2 < 16; ++m2) {
            const float lo = (m2 & 1) ? acc23[m2 >> 1].x : acc01[m2 >> 1].x;
            const float hi = (m2 & 1) ? acc23[m2 >> 1].y : acc01[m2 >> 1].y;
            const float send = h0 ? lo : hi;
            const float mine = h0 ? hi : lo;
            q16[m2] = mine + dppf<0xB1>(send);
        }
        float q8[8];
        #pragma unroll
        for (int m2 = 0; m2 < 8; ++m2) {
            const float lo = q16[2 * m2], hi = q16[2 * m2 + 1];
            const float send = h1 ? lo : hi;
            const float mine = h1 ? hi : lo;
            q8[m2] = mine + dppf<0x4E>(send);
        }
        float q4[4];
        #pragma unroll
        for (int m2 = 0; m2 < 4; ++m2) {
            const float lo = q8[2 * m2], hi = q8[2 * m2 + 1];
            const float send = h2 ? lo : hi;
            const float mine = h2 ? hi : lo;
            q4[m2] = mine + __shfl_xor(send, 4);
        }
        float q2[2];
        #pragma unroll
        for (int m2 = 0; m2 < 2; ++m2) {
            const float lo = q4[2 * m2], hi = q4[2 * m2 + 1];
            const float send = h3 ? lo : hi;
            const float mine = h3 ? hi : lo;
            q2[m2] = mine + __shfl_xor(send, 8);
        }
        // epilogue: lane handles (g=(lane&15)>>2 + 4*hgi, col cg*4+(lane&3))
        #pragma unroll
        for (int hgi = 0; hgi < 2; ++hgi) {
            const int g = ((lane & 15) >> 2) + hgi * 4;
            const float4 u4 = upd4[g];
            const int ts = __float_as_int(u4.x);
            const float u = q2[hgi] + bu;
            const float addv = (u * u4.y) * u4.z;
            te[g][ts][cg * 4 + (tid & 3)] += addv;
        }
        __syncthreads();   // barrier 2: te fully updated

        ag2 = ag2n; gum = gumn; amk = amkn;
    }
}

extern "C" void kernel_launch(void* const* d_in, const int* in_sizes, int n_in,
                              void* d_out, int out_size, void* d_ws, size_t ws_size,
                              hipStream_t stream) {
    const float*         task_embeds  = (const float*)d_in[0];
    const float*         task_nonag   = (const float*)d_in[1];
    const float*         agent_embeds = (const float*)d_in[2];
    const unsigned char* task_mask    = (const unsigned char*)d_in[3];
    const float*         agent_mask   = (const float*)d_in[4];
    const float*         gumbels      = (const float*)d_in[5];
    const float*         W_count      = (const float*)d_in[6];
    const float*         b_count      = (const float*)d_in[7];
    const float*         W_upd        = (const float*)d_in[8];
    const float*         b_upd        = (const float*)d_in[9];
    float* out = (float*)d_out;

    dim3 grid(NBATCH / G);
    dim3 block(NTHREADS);
    hipLaunchKernelGGL(alloc_policy_kernel, grid, block, 0, stream,
                       task_embeds, task_nonag, agent_embeds, task_mask,
                       agent_mask, gumbels, W_count, b_count, W_upd, b_upd, out);
}